// Round 1
// baseline (461.102 us; speedup 1.0000x reference)
//
#include <hip/hip_runtime.h>
#include <hip/hip_cooperative_groups.h>
#include <math.h>

#define D 128

namespace cg = cooperative_groups;

// out_e = tanh( u . f[src_e] + v . f[dst_e] + c )
//   u = W1^T (wa + wb),  v = W1^T (wb - wa),  c = 2*wb.b1 + b2
//   where wa = W2[0,:128], wb = W2[0,128:]
//
// R1 experiment: workspace-free. rocprof showed the 95.7us window is
// 2 x 44.3us 256MiB fillBufferAligned (ws poison) + ~7us of kernels.
// Scratch (uvc: 257 floats, st: 2N floats) now lives in the TAIL of `out`;
// edges whose outputs overlap the scratch are resolved with one grid-wide
// barrier (read-all -> grid.sync -> write-all) in a cooperative kernel.

// Phase 0: fold weights into uvc (interleaved u,v pairs; c at [256]).
__global__ void prep_kernel(const float* __restrict__ W1, const float* __restrict__ b1,
                            const float* __restrict__ W2, const float* __restrict__ b2,
                            float* __restrict__ uvc) {
    __shared__ float su[4 * D];
    __shared__ float sv[4 * D];
    __shared__ float sc[D];
    int tid = threadIdx.x;          // 0..511
    int d = tid & (D - 1);
    int ch = tid >> 7;              // 0..3
    float u = 0.f, v = 0.f;
    int o0 = ch * 32;
    #pragma unroll 8
    for (int k = 0; k < 32; ++k) {
        int o = o0 + k;
        float wa = W2[o];
        float wb = W2[D + o];
        float w1 = W1[o * D + d];   // coalesced across d
        u += (wa + wb) * w1;
        v += (wb - wa) * w1;
    }
    su[ch * D + d] = u;
    sv[ch * D + d] = v;
    if (ch == 0) sc[d] = 2.f * W2[D + d] * b1[d];
    __syncthreads();
    if (tid < D) {
        float uu = su[d] + su[D + d] + su[2 * D + d] + su[3 * D + d];
        float vv = sv[d] + sv[D + d] + sv[2 * D + d] + sv[3 * D + d];
        uvc[2 * d]     = uu;        // interleaved u,v pairs
        uvc[2 * d + 1] = vv;
    }
    if (tid < 64) {                 // parallel c-reduction (was a serial 128-iter loop)
        float p = sc[tid] + sc[tid + 64];
        #pragma unroll
        for (int off = 32; off; off >>= 1) p += __shfl_xor(p, off, 64);
        if (tid == 0) uvc[2 * D] = p + b2[0];
    }
}

// Workspace-free cooperative kernel.
//   uvc = out + U0 (257 floats, written by prep_kernel)
//   st  = out + S0 (2N floats)
//   clean edges [0, U0): writes disjoint from scratch -> direct
//   tail edges  [U0, E): read st into regs -> grid.sync -> write (overwrites scratch)
__global__ __launch_bounds__(256, 4)
void main_coop(const float* __restrict__ feat, const int* __restrict__ src,
               const int* __restrict__ dst, float* __restrict__ out,
               int N, int E, int U0, int S0) {
    const float* uvc = out + U0;
    float2* st = (float2*)(out + S0);
    int tid = blockIdx.x * blockDim.x + threadIdx.x;
    int nthreads = gridDim.x * blockDim.x;

    // ---- phase 1: node dots st[n] = (u.f[n], v.f[n]); 2 nodes per wave ----
    int lane = threadIdx.x & 63;
    int half = lane >> 5;           // 0 or 1
    int l = lane & 31;              // lane within half-wave
    int wave = tid >> 6;
    int nwaves = nthreads >> 6;
    float4 a = ((const float4*)uvc)[2 * l];     // u[4l],v[4l],u[4l+1],v[4l+1]
    float4 b = ((const float4*)uvc)[2 * l + 1]; // u[4l+2],v[4l+2],u[4l+3],v[4l+3]
    for (int node = wave * 2 + half; node < N; node += nwaves * 2) {
        float4 f = ((const float4*)(feat + (size_t)node * D))[l];
        float s = f.x * a.x + f.y * a.z + f.z * b.x + f.w * b.z;
        float t = f.x * a.y + f.y * a.w + f.z * b.y + f.w * b.w;
        #pragma unroll
        for (int off = 16; off; off >>= 1) {  // xor<32 stays within half-wave
            s += __shfl_xor(s, off, 64);
            t += __shfl_xor(t, off, 64);
        }
        if (l == 0) st[node] = make_float2(s, t);
    }

    cg::this_grid().sync();   // st complete + visible device-wide

    float c = uvc[2 * D];

    // ---- phase 2a: clean edges, 4 per thread, vectorized ----
    for (int e0 = tid * 4; e0 < U0; e0 += nthreads * 4) {
        int idx = e0 >> 2;
        int4 si = ((const int4*)src)[idx];
        int4 di = ((const int4*)dst)[idx];
        float2 a0 = st[si.x], a1 = st[si.y], a2 = st[si.z], a3 = st[si.w];
        float2 b0 = st[di.x], b1v = st[di.y], b2v = st[di.z], b3 = st[di.w];
        float4 r;
        r.x = tanhf(a0.x + b0.y + c);
        r.y = tanhf(a1.x + b1v.y + c);
        r.z = tanhf(a2.x + b2v.y + c);
        r.w = tanhf(a3.x + b3.y + c);
        ((float4*)out)[idx] = r;
    }

    // ---- phase 2b: tail edges — read st now, hold result in a register ----
    float rt = 0.f;
    int te = U0 + tid;              // host guarantees E - U0 <= nthreads
    if (te < E) rt = tanhf(st[src[te]].x + st[dst[te]].y + c);

    cg::this_grid().sync();   // ALL st/uvc reads done before any tail write

    if (te < E) out[te] = rt;       // overwrites scratch region with final outputs
}

// ---------- fallback path (previous verified 3-kernel ws version) ----------
__global__ void node_kernel(const float* __restrict__ feat, const float* __restrict__ uvc,
                            float2* __restrict__ st, int N) {
    int wave = (int)((blockIdx.x * blockDim.x + threadIdx.x) >> 6);
    int lane = threadIdx.x & 63;
    int half = lane >> 5;
    int l = lane & 31;
    int node = wave * 2 + half;
    if (node >= N) return;
    float4 f = ((const float4*)(feat + (size_t)node * D))[l];
    float4 a = ((const float4*)uvc)[2 * l];
    float4 b = ((const float4*)uvc)[2 * l + 1];
    float s = f.x * a.x + f.y * a.z + f.z * b.x + f.w * b.z;
    float t = f.x * a.y + f.y * a.w + f.z * b.y + f.w * b.w;
    #pragma unroll
    for (int off = 16; off; off >>= 1) {
        s += __shfl_xor(s, off, 64);
        t += __shfl_xor(t, off, 64);
    }
    if (l == 0) st[node] = make_float2(s, t);
}

__global__ void edge_kernel(const int* __restrict__ src, const int* __restrict__ dst,
                            const float2* __restrict__ st, const float* __restrict__ uvc,
                            float* __restrict__ out, int E) {
    int i = blockIdx.x * blockDim.x + threadIdx.x;
    int e0 = i * 4;
    if (e0 >= E) return;
    float c = uvc[2 * D];
    if (e0 + 3 < E) {
        int4 si = ((const int4*)src)[i];
        int4 di = ((const int4*)dst)[i];
        float2 a0 = st[si.x], a1 = st[si.y], a2 = st[si.z], a3 = st[si.w];
        float2 b0 = st[di.x], b1v = st[di.y], b2v = st[di.z], b3 = st[di.w];
        float4 r;
        r.x = tanhf(a0.x + b0.y + c);
        r.y = tanhf(a1.x + b1v.y + c);
        r.z = tanhf(a2.x + b2v.y + c);
        r.w = tanhf(a3.x + b3.y + c);
        ((float4*)out)[i] = r;
    } else {
        for (int e = e0; e < E; ++e)
            out[e] = tanhf(st[src[e]].x + st[dst[e]].y + c);
    }
}

__global__ void fused_edge_kernel(const float* __restrict__ feat,
                                  const int* __restrict__ src, const int* __restrict__ dst,
                                  const float* __restrict__ uvc, float* __restrict__ out, int E) {
    int wave = (int)((blockIdx.x * blockDim.x + threadIdx.x) >> 6);
    int lane = threadIdx.x & 63;
    if (wave >= E) return;
    int sn = src[wave], dn = dst[wave];
    float2 fs = ((const float2*)(feat + (size_t)sn * D))[lane];
    float2 fd = ((const float2*)(feat + (size_t)dn * D))[lane];
    float2 p = ((const float2*)uvc)[2 * lane];
    float2 q = ((const float2*)uvc)[2 * lane + 1];
    float acc = fs.x * p.x + fs.y * q.x + fd.x * p.y + fd.y * q.y;
    #pragma unroll
    for (int off = 32; off; off >>= 1) acc += __shfl_xor(acc, off, 64);
    if (lane == 0) out[wave] = tanhf(acc + uvc[2 * D]);
}

extern "C" void kernel_launch(void* const* d_in, const int* in_sizes, int n_in,
                              void* d_out, int out_size, void* d_ws, size_t ws_size,
                              hipStream_t stream) {
    const float* feat = (const float*)d_in[0];
    const int*   src  = (const int*)d_in[1];
    const int*   dst  = (const int*)d_in[2];
    const float* W1   = (const float*)d_in[3];
    const float* b1   = (const float*)d_in[4];
    const float* W2   = (const float*)d_in[5];
    const float* b2   = (const float*)d_in[6];
    float* out = (float*)d_out;

    int N = in_sizes[0] / D;
    int E = in_sizes[1];

    // --- Plan A: workspace-free cooperative path ---
    static int coop_blocks = 0;
    if (coop_blocks == 0) {
        int per_cu = 0;
        if (hipOccupancyMaxActiveBlocksPerMultiprocessor(&per_cu, main_coop, 256, (size_t)0)
                != hipSuccess || per_cu <= 0)
            per_cu = 4;              // __launch_bounds__(256,4) guarantees >= 4
        if (per_cu > 8) per_cu = 8;
        coop_blocks = per_cu * 256;  // MI355X: 256 CUs; co-resident by construction
    }

    bool done = false;
    int S0 = (E - 2 * N) & ~1;                   // st at out[S0 .. S0+2N)
    if (S0 >= 528) {
        int U0 = (S0 - 512) & ~15;               // uvc at out[U0 .. U0+257); 16-elem aligned
        long tail = (long)E - (long)U0;          // tail edges need 1 reg per thread
        if (U0 >= 0 && tail <= (long)coop_blocks * 256) {
            prep_kernel<<<1, 512, 0, stream>>>(W1, b1, W2, b2, out + U0);
            void* args[8] = {(void*)&feat, (void*)&src, (void*)&dst, (void*)&out,
                             (void*)&N, (void*)&E, (void*)&U0, (void*)&S0};
            hipError_t err = hipLaunchCooperativeKernel(main_coop, dim3(coop_blocks),
                                                        dim3(256), args, 0, stream);
            if (err == hipSuccess) {
                done = true;
            } else {
                (void)hipGetLastError();         // clear; fall back to ws path
            }
        }
    }
    if (done) return;

    // --- Plan B: previous verified workspace path ---
    float* uvc = (float*)d_ws;
    float2* st = (float2*)((float*)d_ws + 512);
    size_t needed = (512 + 2 * (size_t)N) * sizeof(float);

    prep_kernel<<<1, 512, 0, stream>>>(W1, b1, W2, b2, uvc);

    if (ws_size >= needed) {
        int nblocks = (N + 7) / 8;
        node_kernel<<<nblocks, 256, 0, stream>>>(feat, uvc, st, N);
        int nthreads = (E + 3) / 4;
        edge_kernel<<<(nthreads + 255) / 256, 256, 0, stream>>>(src, dst, st, uvc, out, E);
    } else {
        int nblocks = (E + 3) / 4;
        fused_edge_kernel<<<nblocks, 256, 0, stream>>>(feat, src, dst, uvc, out, E);
    }
}

// Round 2
// 94.574 us; speedup vs baseline: 4.8756x; 4.8756x over previous
//
#include <hip/hip_runtime.h>
#include <math.h>

#define D 128

// out_e = tanh( u . f[src_e] + v . f[dst_e] + c )
//   u = W1^T (wa + wb),  v = W1^T (wb - wa),  c = 2*wb.b1 + b2
//   where wa = W2[0,:128], wb = W2[0,128:]
//
// R2: REVERT of the R1 cooperative experiment.
//   R1 measured: cg::this_grid().sync() costs ~350us (VALUBusy 0.7%) and the
//   256MiB ws-poison fills (2 x 44.3us) are unconditional + in-window, so
//   avoiding d_ws buys nothing. Kernel boundaries are the cheap barrier.
//   Structure: prep (fold weights) -> node (st[n] = (u.f, v.f)) -> edge
//   (gather + tanh). Mandatory HBM traffic 35.2 MB ~= 5.6us; fills ~= 88.6us.

// Phase 0: fold weights. 512 threads: d = tid&127, o-chunk = tid>>7.
__global__ void prep_kernel(const float* __restrict__ W1, const float* __restrict__ b1,
                            const float* __restrict__ W2, const float* __restrict__ b2,
                            float* __restrict__ uvc) {
    __shared__ float su[4 * D];
    __shared__ float sv[4 * D];
    __shared__ float sc[D];
    int tid = threadIdx.x;          // 0..511
    int d = tid & (D - 1);
    int ch = tid >> 7;              // 0..3
    float u = 0.f, v = 0.f;
    int o0 = ch * 32;
    #pragma unroll 8
    for (int k = 0; k < 32; ++k) {
        int o = o0 + k;
        float wa = W2[o];
        float wb = W2[D + o];
        float w1 = W1[o * D + d];   // coalesced across d
        u += (wa + wb) * w1;
        v += (wb - wa) * w1;
    }
    su[ch * D + d] = u;
    sv[ch * D + d] = v;
    if (ch == 0) sc[d] = 2.f * W2[D + d] * b1[d];
    __syncthreads();
    if (tid < D) {
        float uu = su[d] + su[D + d] + su[2 * D + d] + su[3 * D + d];
        float vv = sv[d] + sv[D + d] + sv[2 * D + d] + sv[3 * D + d];
        uvc[2 * d]     = uu;        // interleaved u,v pairs
        uvc[2 * d + 1] = vv;
    }
    if (tid < 64) {                 // parallel c-reduction (was serial 128-iter)
        float p = sc[tid] + sc[tid + 64];
        #pragma unroll
        for (int off = 32; off; off >>= 1) p += __shfl_xor(p, off, 64);
        if (tid == 0) uvc[2 * D] = p + b2[0];
    }
}

// Phase 1: st[n] = (u.f[n], v.f[n]). Two nodes per wave, float4 per lane.
__global__ void node_kernel(const float* __restrict__ feat, const float* __restrict__ uvc,
                            float2* __restrict__ st, int N) {
    int wave = (int)((blockIdx.x * blockDim.x + threadIdx.x) >> 6);
    int lane = threadIdx.x & 63;
    int half = lane >> 5;           // 0 or 1
    int l = lane & 31;              // lane within half-wave
    int node = wave * 2 + half;
    if (node >= N) return;
    float4 f = ((const float4*)(feat + (size_t)node * D))[l];
    // uvc interleaved: pairs (u[d],v[d]); lane covers d = 4l..4l+3
    float4 a = ((const float4*)uvc)[2 * l];     // u[4l],v[4l],u[4l+1],v[4l+1]
    float4 b = ((const float4*)uvc)[2 * l + 1]; // u[4l+2],v[4l+2],u[4l+3],v[4l+3]
    float s = f.x * a.x + f.y * a.z + f.z * b.x + f.w * b.z;
    float t = f.x * a.y + f.y * a.w + f.z * b.y + f.w * b.w;
    #pragma unroll
    for (int off = 16; off; off >>= 1) {  // xor<32 stays within half-wave
        s += __shfl_xor(s, off, 64);
        t += __shfl_xor(t, off, 64);
    }
    if (l == 0) st[node] = make_float2(s, t);
}

// Phase 2: per-edge gather + tanh. 4 edges/thread; st gather = one 8B load/node.
__global__ void edge_kernel(const int* __restrict__ src, const int* __restrict__ dst,
                            const float2* __restrict__ st, const float* __restrict__ uvc,
                            float* __restrict__ out, int E) {
    int i = blockIdx.x * blockDim.x + threadIdx.x;
    int e0 = i * 4;
    if (e0 >= E) return;
    float c = uvc[2 * D];
    if (e0 + 3 < E) {
        int4 si = ((const int4*)src)[i];
        int4 di = ((const int4*)dst)[i];
        float2 a0 = st[si.x], a1 = st[si.y], a2 = st[si.z], a3 = st[si.w];
        float2 b0 = st[di.x], b1v = st[di.y], b2v = st[di.z], b3 = st[di.w];
        float4 r;
        r.x = tanhf(a0.x + b0.y + c);
        r.y = tanhf(a1.x + b1v.y + c);
        r.z = tanhf(a2.x + b2v.y + c);
        r.w = tanhf(a3.x + b3.y + c);
        ((float4*)out)[i] = r;
    } else {
        for (int e = e0; e < E; ++e)
            out[e] = tanhf(st[src[e]].x + st[dst[e]].y + c);
    }
}

// Fallback if workspace too small: fused per-edge dot (wave per edge).
__global__ void fused_edge_kernel(const float* __restrict__ feat,
                                  const int* __restrict__ src, const int* __restrict__ dst,
                                  const float* __restrict__ uvc, float* __restrict__ out, int E) {
    int wave = (int)((blockIdx.x * blockDim.x + threadIdx.x) >> 6);
    int lane = threadIdx.x & 63;
    if (wave >= E) return;
    int sn = src[wave], dn = dst[wave];
    float2 fs = ((const float2*)(feat + (size_t)sn * D))[lane];
    float2 fd = ((const float2*)(feat + (size_t)dn * D))[lane];
    float2 p = ((const float2*)uvc)[2 * lane];       // u,v for d=2*lane
    float2 q = ((const float2*)uvc)[2 * lane + 1];   // u,v for d=2*lane+1
    float acc = fs.x * p.x + fs.y * q.x + fd.x * p.y + fd.y * q.y;
    #pragma unroll
    for (int off = 32; off; off >>= 1) acc += __shfl_xor(acc, off, 64);
    if (lane == 0) out[wave] = tanhf(acc + uvc[2 * D]);
}

extern "C" void kernel_launch(void* const* d_in, const int* in_sizes, int n_in,
                              void* d_out, int out_size, void* d_ws, size_t ws_size,
                              hipStream_t stream) {
    const float* feat = (const float*)d_in[0];
    const int*   src  = (const int*)d_in[1];
    const int*   dst  = (const int*)d_in[2];
    const float* W1   = (const float*)d_in[3];
    const float* b1   = (const float*)d_in[4];
    const float* W2   = (const float*)d_in[5];
    const float* b2   = (const float*)d_in[6];
    float* out = (float*)d_out;

    int N = in_sizes[0] / D;
    int E = in_sizes[1];

    float* uvc = (float*)d_ws;              // 257 floats used, pad to 512
    float2* st = (float2*)((float*)d_ws + 512);
    size_t needed = (512 + 2 * (size_t)N) * sizeof(float);

    prep_kernel<<<1, 512, 0, stream>>>(W1, b1, W2, b2, uvc);

    if (ws_size >= needed) {
        // node pass: 2 nodes/wave, 4 waves per 256-thread block -> 8 nodes/block
        int nblocks = (N + 7) / 8;
        node_kernel<<<nblocks, 256, 0, stream>>>(feat, uvc, st, N);
        // edge pass: 4 edges per thread
        int nthreads = (E + 3) / 4;
        edge_kernel<<<(nthreads + 255) / 256, 256, 0, stream>>>(src, dst, st, uvc, out, E);
    } else {
        int nblocks = (E + 3) / 4;          // wave per edge
        fused_edge_kernel<<<nblocks, 256, 0, stream>>>(feat, src, dst, uvc, out, E);
    }
}